// Round 2
// baseline (6528.248 us; speedup 1.0000x reference)
//
#include <hip/hip_runtime.h>
#include <cstddef>

// Problem constants (fixed by reference)
constexpr int Bc  = 2;
constexpr int Tc  = 2048;
constexpr int BTc = Bc * Tc;      // 4096 rows
constexpr int Dc  = 1024;
constexpr int Hc  = 16;
constexpr int HDc = 64;
constexpr int DFc = 4096;
constexpr int Vc  = 32000;
constexpr int Lc  = 4;
constexpr float EPSc = 1e-5f;

typedef unsigned short u16;
typedef __attribute__((ext_vector_type(8))) short     bf16x8;
typedef __attribute__((ext_vector_type(4))) float     f32x4;
typedef __attribute__((ext_vector_type(8))) unsigned short u16x8;
typedef __attribute__((ext_vector_type(4))) unsigned short u16x4;

__device__ inline u16 f2bf(float f) {
    union { float f; unsigned int u; } x; x.f = f;
    unsigned int r = x.u + 0x7fffu + ((x.u >> 16) & 1u);  // RNE
    return (u16)(r >> 16);
}
__device__ inline float bf2f(u16 h) {
    union { unsigned int u; float f; } x; x.u = ((unsigned int)h) << 16;
    return x.f;
}

__device__ inline void gload_lds16(const void* g, void* l) {
    __builtin_amdgcn_global_load_lds(
        (const __attribute__((address_space(1))) void*)g,
        (__attribute__((address_space(3))) void*)l, 16, 0, 0);
}

// ---------------------------------------------------------------------------
// Embedding: x[bt,:] = tok_emb[idx[bt],:] + pos_emb[bt % T,:]  (fp32)
// ---------------------------------------------------------------------------
__global__ __launch_bounds__(256) void embed_kernel(
    const int* __restrict__ idx, const float* __restrict__ tok,
    const float* __restrict__ pos, float* __restrict__ x)
{
    const int bt = blockIdx.x;
    const int t  = threadIdx.x;
    const int token = idx[bt];
    const int tt = bt & (Tc - 1);
    const float4 tv = *(const float4*)(tok + (size_t)token * Dc + t * 4);
    const float4 pv = *(const float4*)(pos + (size_t)tt * Dc + t * 4);
    float4 o;
    o.x = tv.x + pv.x; o.y = tv.y + pv.y; o.z = tv.z + pv.z; o.w = tv.w + pv.w;
    *(float4*)(x + (size_t)bt * Dc + t * 4) = o;
}

// ---------------------------------------------------------------------------
// LayerNorm over D=1024 (fp32 in, bf16 out): one block per row
// ---------------------------------------------------------------------------
__global__ __launch_bounds__(256) void ln_bf16_kernel(
    const float* __restrict__ x, const float* __restrict__ s,
    const float* __restrict__ b, u16* __restrict__ out)
{
    const int row = blockIdx.x;
    const int t = threadIdx.x;
    const float4 v = *(const float4*)(x + (size_t)row * Dc + t * 4);
    float sum = v.x + v.y + v.z + v.w;
    float sq  = v.x*v.x + v.y*v.y + v.z*v.z + v.w*v.w;
    #pragma unroll
    for (int off = 1; off < 64; off <<= 1) {
        sum += __shfl_xor(sum, off);
        sq  += __shfl_xor(sq,  off);
    }
    __shared__ float red[10];
    const int wave = t >> 6, lane = t & 63;
    if (lane == 0) { red[wave] = sum; red[4 + wave] = sq; }
    __syncthreads();
    if (t == 0) {
        const float S = red[0] + red[1] + red[2] + red[3];
        const float Q = red[4] + red[5] + red[6] + red[7];
        const float mu  = S * (1.0f / Dc);
        const float var = Q * (1.0f / Dc) - mu * mu;
        red[8] = mu;
        red[9] = rsqrtf(var + EPSc);
    }
    __syncthreads();
    const float mu = red[8], rstd = red[9];
    const float4 sv = *(const float4*)(s + t * 4);
    const float4 bv = *(const float4*)(b + t * 4);
    u16x4 o;
    o[0] = f2bf((v.x - mu) * rstd * sv.x + bv.x);
    o[1] = f2bf((v.y - mu) * rstd * sv.y + bv.y);
    o[2] = f2bf((v.z - mu) * rstd * sv.z + bv.z);
    o[3] = f2bf((v.w - mu) * rstd * sv.w + bv.w);
    *(u16x4*)(out + (size_t)row * Dc + t * 4) = o;
}

// ---------------------------------------------------------------------------
// Transpose + fp32->bf16 convert: W[K][N] -> Wt[N][K].  64x64 tiles.
// ---------------------------------------------------------------------------
__global__ __launch_bounds__(256) void transpose_conv_kernel(
    const float* __restrict__ W, u16* __restrict__ Wt, int K, int N)
{
    __shared__ float tile[64][65];
    const int n0 = blockIdx.x * 64;
    const int k0 = blockIdx.y * 64;
    const int t  = threadIdx.x;
    const int c4 = (t & 15) * 4;
    #pragma unroll
    for (int i = 0; i < 4; ++i) {
        const int kk = i * 16 + (t >> 4);
        const float4 v = *(const float4*)(W + (size_t)(k0 + kk) * N + n0 + c4);
        tile[c4 + 0][kk] = v.x;
        tile[c4 + 1][kk] = v.y;
        tile[c4 + 2][kk] = v.z;
        tile[c4 + 3][kk] = v.w;
    }
    __syncthreads();
    #pragma unroll
    for (int i = 0; i < 4; ++i) {
        const int nn = i * 16 + (t >> 4);
        u16x4 o;
        o[0] = f2bf(tile[nn][c4 + 0]);
        o[1] = f2bf(tile[nn][c4 + 1]);
        o[2] = f2bf(tile[nn][c4 + 2]);
        o[3] = f2bf(tile[nn][c4 + 3]);
        *(u16x4*)(Wt + (size_t)(n0 + nn) * K + k0 + c4) = o;
    }
}

// ---------------------------------------------------------------------------
// bf16 MFMA GEMM (m97 structure): C[M,N] = f(A[M,K] @ Wt[N,K]^T + bias)
// 128x128 tile, BK=64, 256 threads = 4 waves (2x2), 4x4 16x16x32 frags/wave.
// LDS layout [kc][m][8] (8-elem k-chunks): global_load_lds linear dest AND
// conflict-free ds_read_b128 fragment reads.
// MODE: 0 = fp32 out, 1 = fp32 out + residual, 2 = relu -> bf16, 3 = bf16
// ---------------------------------------------------------------------------
template<int MODE>
__global__ __launch_bounds__(256) void gemm_bf16_kernel(
    const u16* __restrict__ A,    // [M][K] bf16
    const u16* __restrict__ Wt,   // [N][K] bf16 (pre-transposed)
    const float* __restrict__ bias,
    const float* __restrict__ res,
    void* __restrict__ C,
    int M, int N, int K)
{
    __shared__ __align__(16) u16 sA[8 * 128 * 8];
    __shared__ __align__(16) u16 sB[8 * 128 * 8];

    const int bn = blockIdx.x * 128;
    const int bm = blockIdx.y * 128;
    const int t    = threadIdx.x;
    const int lane = t & 63;
    const int w    = t >> 6;
    const int wr   = w >> 1, wc = w & 1;

    f32x4 acc[4][4];
    #pragma unroll
    for (int m = 0; m < 4; ++m)
        #pragma unroll
        for (int n = 0; n < 4; ++n)
            acc[m][n] = (f32x4){0.f, 0.f, 0.f, 0.f};

    for (int k0 = 0; k0 < K; k0 += 64) {
        __syncthreads();   // prev iteration's LDS reads done
        #pragma unroll
        for (int ii = 0; ii < 4; ++ii) {
            const int i  = w * 4 + ii;          // 0..15 across waves
            const int kc = i >> 1;
            const int mh = (i & 1) * 64;
            const u16* ga = A  + (size_t)(bm + mh + lane) * K + k0 + kc * 8;
            const u16* gb = Wt + (size_t)(bn + mh + lane) * K + k0 + kc * 8;
            gload_lds16(ga, &sA[(kc * 128 + mh) * 8]);
            gload_lds16(gb, &sB[(kc * 128 + mh) * 8]);
        }
        __syncthreads();   // compiler drains vmcnt before barrier

        #pragma unroll
        for (int s = 0; s < 2; ++s) {
            const int kcs = s * 4 + (lane >> 4);
            bf16x8 af[4], bfr[4];
            #pragma unroll
            for (int m = 0; m < 4; ++m) {
                const int row = wr * 64 + m * 16 + (lane & 15);
                af[m] = *(const bf16x8*)&sA[(kcs * 128 + row) * 8];
            }
            #pragma unroll
            for (int n = 0; n < 4; ++n) {
                const int col = wc * 64 + n * 16 + (lane & 15);
                bfr[n] = *(const bf16x8*)&sB[(kcs * 128 + col) * 8];
            }
            #pragma unroll
            for (int m = 0; m < 4; ++m)
                #pragma unroll
                for (int n = 0; n < 4; ++n)
                    acc[m][n] = __builtin_amdgcn_mfma_f32_16x16x32_bf16(
                        af[m], bfr[n], acc[m][n], 0, 0, 0);
        }
    }

    // epilogue: C/D layout col=lane&15, row=(lane>>4)*4+reg  [m89-verified]
    float bv[4];
    #pragma unroll
    for (int n = 0; n < 4; ++n)
        bv[n] = bias[bn + wc * 64 + n * 16 + (lane & 15)];

    #pragma unroll
    for (int m = 0; m < 4; ++m) {
        #pragma unroll
        for (int r = 0; r < 4; ++r) {
            const int row = bm + wr * 64 + m * 16 + (lane >> 4) * 4 + r;
            #pragma unroll
            for (int n = 0; n < 4; ++n) {
                const int col = bn + wc * 64 + n * 16 + (lane & 15);
                float v = acc[m][n][r] + bv[n];
                if (MODE == 2) v = fmaxf(v, 0.0f);
                if (MODE == 1) v += res[(size_t)row * N + col];
                if (MODE <= 1) ((float*)C)[(size_t)row * N + col] = v;
                else           ((u16*)C)[(size_t)row * N + col] = f2bf(v);
            }
        }
    }
}

// ---------------------------------------------------------------------------
// Flash attention (causal), bf16 in / bf16 out, fp32 compute.
// One block per (b, h, 64-row q tile). qkv: [BT][3072], y: [BT][1024].
// ---------------------------------------------------------------------------
__global__ __launch_bounds__(256) void attn_kernel(
    const u16* __restrict__ qkv, u16* __restrict__ y)
{
    const int qb = blockIdx.x;
    const int h  = blockIdx.y;
    const int b  = blockIdx.z;
    const int t  = threadIdx.x;
    const int r  = t >> 2;
    const int q4 = t & 3;

    __shared__ float sK[64][72];
    __shared__ float sV[64][72];
    __shared__ float sS[64][65];

    const int q0 = qb * 64;
    const int row_t = q0 + r;

    float qreg[64];
    const u16* qptr = qkv + (size_t)(b * Tc + row_t) * (3 * Dc) + h * HDc;
    #pragma unroll
    for (int i = 0; i < 8; ++i) {
        const u16x8 qv = *(const u16x8*)(qptr + i * 8);
        #pragma unroll
        for (int j = 0; j < 8; ++j) qreg[i * 8 + j] = bf2f(qv[j]);
    }

    float m = -1e30f, l = 0.0f;
    float acc[16] = {};

    const int nchunks = qb + 1;
    for (int ch = 0; ch < nchunks; ++ch) {
        const int c0 = ch * 64;
        __syncthreads();
        #pragma unroll
        for (int i = 0; i < 2; ++i) {
            const int flat = i * 2048 + t * 8;
            const int cr = flat >> 6, cc = flat & 63;
            const u16* kp = qkv + (size_t)(b * Tc + c0 + cr) * (3 * Dc) + Dc + h * HDc + cc;
            const u16x8 kv = *(const u16x8*)kp;
            const u16x8 vv = *(const u16x8*)(kp + Dc);
            #pragma unroll
            for (int j = 0; j < 8; ++j) {
                sK[cr][cc + j] = bf2f(kv[j]);
                sV[cr][cc + j] = bf2f(vv[j]);
            }
        }
        __syncthreads();

        float p[16];
        float mloc = -1e30f;
        #pragma unroll
        for (int j = 0; j < 16; ++j) {
            const int c = j * 4 + q4;
            float dot = 0.0f;
            #pragma unroll
            for (int kk = 0; kk < 64; kk += 4) {
                const float4 kv = *(const float4*)&sK[c][kk];
                dot = fmaf(qreg[kk + 0], kv.x, dot);
                dot = fmaf(qreg[kk + 1], kv.y, dot);
                dot = fmaf(qreg[kk + 2], kv.z, dot);
                dot = fmaf(qreg[kk + 3], kv.w, dot);
            }
            dot *= 0.125f;
            if (c0 + c > row_t) dot = -1e30f;
            p[j] = dot;
            mloc = fmaxf(mloc, dot);
        }
        mloc = fmaxf(mloc, __shfl_xor(mloc, 1));
        mloc = fmaxf(mloc, __shfl_xor(mloc, 2));
        const float mnew = fmaxf(m, mloc);
        const float corr = __expf(m - mnew);
        float psum = 0.0f;
        #pragma unroll
        for (int j = 0; j < 16; ++j) {
            const float e = __expf(p[j] - mnew);
            sS[r][j * 4 + q4] = e;
            psum += e;
        }
        psum += __shfl_xor(psum, 1);
        psum += __shfl_xor(psum, 2);
        l = l * corr + psum;
        m = mnew;
        #pragma unroll
        for (int i = 0; i < 16; ++i) acc[i] *= corr;
        __syncthreads();

        const int d0 = q4 * 16;
        #pragma unroll
        for (int c = 0; c < 64; ++c) {
            const float sc = sS[r][c];
            #pragma unroll
            for (int i = 0; i < 16; i += 4) {
                const float4 vv = *(const float4*)&sV[c][d0 + i];
                acc[i + 0] = fmaf(sc, vv.x, acc[i + 0]);
                acc[i + 1] = fmaf(sc, vv.y, acc[i + 1]);
                acc[i + 2] = fmaf(sc, vv.z, acc[i + 2]);
                acc[i + 3] = fmaf(sc, vv.w, acc[i + 3]);
            }
        }
    }

    const float inv_l = 1.0f / l;
    u16* yp = y + (size_t)(b * Tc + row_t) * Dc + h * HDc + q4 * 16;
    #pragma unroll
    for (int i = 0; i < 16; i += 4) {
        u16x4 o;
        o[0] = f2bf(acc[i + 0] * inv_l);
        o[1] = f2bf(acc[i + 1] * inv_l);
        o[2] = f2bf(acc[i + 2] * inv_l);
        o[3] = f2bf(acc[i + 3] * inv_l);
        *(u16x4*)(yp + i) = o;
    }
}

// ---------------------------------------------------------------------------
// Per-row loss: row_loss[row] = logsumexp(logits[row,:]) - logits[row,tgt]
// ---------------------------------------------------------------------------
__global__ __launch_bounds__(256) void loss_row_kernel(
    const float* __restrict__ logits, const int* __restrict__ targets,
    float* __restrict__ row_loss)
{
    const int row = blockIdx.x;
    const float* lp = logits + (size_t)row * Vc;
    float m = -1e30f, s = 0.0f;
    for (int c = threadIdx.x; c < Vc; c += 256) {
        const float v = lp[c];
        const float mn = fmaxf(m, v);
        s = s * __expf(m - mn) + __expf(v - mn);
        m = mn;
    }
    #pragma unroll
    for (int off = 1; off < 64; off <<= 1) {
        const float m2 = __shfl_xor(m, off);
        const float s2 = __shfl_xor(s, off);
        const float mn = fmaxf(m, m2);
        s = s * __expf(m - mn) + s2 * __expf(m2 - mn);
        m = mn;
    }
    __shared__ float rm[4], rs[4];
    const int wave = threadIdx.x >> 6, lane = threadIdx.x & 63;
    if (lane == 0) { rm[wave] = m; rs[wave] = s; }
    __syncthreads();
    if (threadIdx.x == 0) {
        float M = rm[0], S = rs[0];
        #pragma unroll
        for (int w = 1; w < 4; ++w) {
            const float mn = fmaxf(M, rm[w]);
            S = S * __expf(M - mn) + rs[w] * __expf(rm[w] - mn);
            M = mn;
        }
        const float lse = M + __logf(S);
        row_loss[row] = lse - lp[targets[row]];
    }
}

__global__ __launch_bounds__(256) void loss_reduce_kernel(
    const float* __restrict__ row_loss, float* __restrict__ out)
{
    float s = 0.0f;
    for (int i = threadIdx.x; i < BTc; i += 256) s += row_loss[i];
    #pragma unroll
    for (int off = 1; off < 64; off <<= 1) s += __shfl_xor(s, off);
    __shared__ float r[4];
    if ((threadIdx.x & 63) == 0) r[threadIdx.x >> 6] = s;
    __syncthreads();
    if (threadIdx.x == 0) out[0] = (r[0] + r[1] + r[2] + r[3]) * (1.0f / BTc);
}

// ---------------------------------------------------------------------------
// Host-side orchestration
// ---------------------------------------------------------------------------
extern "C" void kernel_launch(void* const* d_in, const int* in_sizes, int n_in,
                              void* d_out, int out_size, void* d_ws, size_t ws_size,
                              hipStream_t stream)
{
    const int*   idx     = (const int*)  d_in[0];
    const int*   targets = (const int*)  d_in[1];
    const float* tok_emb = (const float*)d_in[2];
    const float* pos_emb = (const float*)d_in[3];
    const float* qkv_w   = (const float*)d_in[4];
    const float* qkv_b   = (const float*)d_in[5];
    const float* proj_w  = (const float*)d_in[6];
    const float* proj_b  = (const float*)d_in[7];
    const float* ln1_s   = (const float*)d_in[8];
    const float* ln1_b   = (const float*)d_in[9];
    const float* ln2_s   = (const float*)d_in[10];
    const float* ln2_b   = (const float*)d_in[11];
    const float* ffn_w1  = (const float*)d_in[12];
    const float* ffn_b1  = (const float*)d_in[13];
    const float* ffn_w2  = (const float*)d_in[14];
    const float* ffn_b2  = (const float*)d_in[15];
    const float* lnf_s   = (const float*)d_in[16];
    const float* lnf_b   = (const float*)d_in[17];
    const float* head_w  = (const float*)d_in[18];
    const float* head_b  = (const float*)d_in[19];

    float* out = (float*)d_out;

    // Workspace carve (256B aligned chunks), total ~133 MB
    char* p = (char*)d_ws;
    auto carve = [&](size_t bytes) { char* r = p; p += (bytes + 255) & ~(size_t)255; return r; };
    float* x        = (float*)carve((size_t)BTc * Dc * 4);
    float* row_loss = (float*)carve((size_t)BTc * 4);
    u16*   h_bf     = (u16*)  carve((size_t)BTc * Dc * 2);
    u16*   y_bf     = (u16*)  carve((size_t)BTc * Dc * 2);
    u16*   act_bf   = (u16*)  carve((size_t)BTc * DFc * 2);   // qkv / ffn-mid
    u16*   w_bf     = (u16*)  carve((size_t)Vc * Dc * 2);     // per-GEMM Wt

    const dim3 blk(256);

    auto transpose = [&](const float* W, int K, int N) {
        transpose_conv_kernel<<<dim3(N / 64, K / 64), blk, 0, stream>>>(W, w_bf, K, N);
    };
    auto gemm = [&](int mode, const u16* A, const float* bias, const float* res,
                    void* C, int M, int N, int K) {
        dim3 grid(N / 128, M / 128);
        switch (mode) {
            case 0: gemm_bf16_kernel<0><<<grid, blk, 0, stream>>>(A, w_bf, bias, res, C, M, N, K); break;
            case 1: gemm_bf16_kernel<1><<<grid, blk, 0, stream>>>(A, w_bf, bias, res, C, M, N, K); break;
            case 2: gemm_bf16_kernel<2><<<grid, blk, 0, stream>>>(A, w_bf, bias, res, C, M, N, K); break;
            default:gemm_bf16_kernel<3><<<grid, blk, 0, stream>>>(A, w_bf, bias, res, C, M, N, K); break;
        }
    };

    embed_kernel<<<BTc, blk, 0, stream>>>(idx, tok_emb, pos_emb, x);

    for (int l = 0; l < Lc; ++l) {
        // --- attention block ---
        ln_bf16_kernel<<<BTc, blk, 0, stream>>>(x, ln1_s + l * Dc, ln1_b + l * Dc, h_bf);
        transpose(qkv_w + (size_t)l * Dc * 3 * Dc, Dc, 3 * Dc);
        gemm(3, h_bf, qkv_b + (size_t)l * 3 * Dc, nullptr, act_bf, BTc, 3 * Dc, Dc);
        attn_kernel<<<dim3(Tc / 64, Hc, Bc), blk, 0, stream>>>(act_bf, y_bf);
        transpose(proj_w + (size_t)l * Dc * Dc, Dc, Dc);
        gemm(1, y_bf, proj_b + (size_t)l * Dc, x, x, BTc, Dc, Dc);
        // --- FFN block ---
        ln_bf16_kernel<<<BTc, blk, 0, stream>>>(x, ln2_s + l * Dc, ln2_b + l * Dc, h_bf);
        transpose(ffn_w1 + (size_t)l * Dc * DFc, Dc, DFc);
        gemm(2, h_bf, ffn_b1 + (size_t)l * DFc, nullptr, act_bf, BTc, DFc, Dc);
        transpose(ffn_w2 + (size_t)l * DFc * Dc, DFc, Dc);
        gemm(1, act_bf, ffn_b2 + (size_t)l * Dc, x, x, BTc, Dc, DFc);
    }

    ln_bf16_kernel<<<BTc, blk, 0, stream>>>(x, lnf_s, lnf_b, h_bf);
    transpose(head_w, Dc, Vc);
    gemm(0, h_bf, head_b, nullptr, out, BTc, Vc, Dc);

    loss_row_kernel<<<BTc, blk, 0, stream>>>(out, targets, row_loss);
    loss_reduce_kernel<<<1, blk, 0, stream>>>(row_loss, out + (size_t)BTc * Vc);
}